// Round 1
// baseline (716.374 us; speedup 1.0000x reference)
//
#include <hip/hip_runtime.h>
#include <hip/hip_bf16.h>
#include <math.h>

#define NQ 13294
#define NV 13294
#define M_ROWS (2*NQ)

__device__ __forceinline__ float4 ld4(const float* p){ return *(const float4*)p; }

// C = (A [+ A2]) @ B + bias [+ RES]; A: MxK row-major, B: KxN row-major, C: MxN
template<bool ADD_A2, bool ADD_RES>
__global__ __launch_bounds__(256) void gemm_f32(
    const float* __restrict__ A, const float* __restrict__ A2,
    const float* __restrict__ B, const float* __restrict__ bias,
    const float* __restrict__ RES, float* __restrict__ C,
    int M, int N, int K)
{
  __shared__ float As[16][64];   // [k][m]
  __shared__ float Bs[16][64];   // [k][n]
  const int tid  = threadIdx.x;
  const int trow = tid >> 4;     // 0..15
  const int tcol = tid & 15;     // 0..15
  const int brow = blockIdx.y * 64;
  const int bcol = blockIdx.x * 64;

  const int lar = tid >> 2;          // A tile row 0..63
  const int lak = (tid & 3) * 4;     // A tile k   0,4,8,12
  const int lbr = tid >> 4;          // B tile row 0..15
  const int lbc = (tid & 15) * 4;    // B tile col

  const int arow = brow + lar;
  const bool a_ok = arow < M;

  float acc[4][4] = {};

  for (int k0 = 0; k0 < K; k0 += 16) {
    float4 a4 = make_float4(0.f,0.f,0.f,0.f);
    if (a_ok) {
      a4 = ld4(A + (size_t)arow*K + k0 + lak);
      if (ADD_A2) {
        float4 p4 = ld4(A2 + (size_t)arow*K + k0 + lak);
        a4.x += p4.x; a4.y += p4.y; a4.z += p4.z; a4.w += p4.w;
      }
    }
    float4 b4 = ld4(B + (size_t)(k0 + lbr)*N + bcol + lbc);

    __syncthreads();
    As[lak+0][lar] = a4.x;
    As[lak+1][lar] = a4.y;
    As[lak+2][lar] = a4.z;
    As[lak+3][lar] = a4.w;
    *(float4*)&Bs[lbr][lbc] = b4;
    __syncthreads();

    #pragma unroll
    for (int kk = 0; kk < 16; ++kk) {
      float4 av = *(const float4*)&As[kk][trow*4];
      float4 bv = *(const float4*)&Bs[kk][tcol*4];
      float aa[4] = {av.x, av.y, av.z, av.w};
      float bb[4] = {bv.x, bv.y, bv.z, bv.w};
      #pragma unroll
      for (int i = 0; i < 4; ++i)
        #pragma unroll
        for (int j = 0; j < 4; ++j)
          acc[i][j] = fmaf(aa[i], bb[j], acc[i][j]);
    }
  }

  #pragma unroll
  for (int i = 0; i < 4; ++i) {
    int r = brow + trow*4 + i;
    if (r >= M) continue;
    #pragma unroll
    for (int j = 0; j < 4; ++j) {
      int c = bcol + tcol*4 + j;
      float vv = acc[i][j] + bias[c];
      if (ADD_RES) vv += RES[(size_t)r*N + c];
      C[(size_t)r*N + c] = vv;
    }
  }
}

// Multi-scale deformable sampling.
// v:      (bs, NV, 256)   value projection, embed idx = h*32+d
// off:    (bs, NQ, 8, 4, 4, 2)  flat
// lgt:    (bs, NQ, 8, 16)       attn logits (pre-softmax)
// ref:    (bs, NQ, 4, 2)
// attout: (bs, NQ, 256)  embed idx = h*32+d
__global__ __launch_bounds__(256) void msda_sample(
    const float* __restrict__ v, const float* __restrict__ off,
    const float* __restrict__ lgt, const float* __restrict__ ref,
    float* __restrict__ attout)
{
  constexpr int LH[4] = {100, 50, 25, 13};
  constexpr int LW[4] = {100, 50, 25, 13};
  constexpr int LS[4] = {0, 10000, 12500, 13125};

  const int tid  = threadIdx.x;
  const int g    = blockIdx.x * 8 + (tid >> 5);   // (b*NQ+q)*8 + h
  const int lane = tid & 31;                       // channel d
  if (g >= 2*NQ*8) return;

  const int h  = g & 7;
  const int bq = g >> 3;          // b*NQ + q
  const int b  = bq / NQ;

  // softmax over 16 logits (redundant per lane, registers only)
  const float* lg = lgt + ((size_t)bq*8 + h)*16;
  float w[16], mx = -1e30f;
  #pragma unroll
  for (int i = 0; i < 16; ++i) { w[i] = lg[i]; mx = fmaxf(mx, w[i]); }
  float s = 0.f;
  #pragma unroll
  for (int i = 0; i < 16; ++i) { w[i] = __expf(w[i] - mx); s += w[i]; }
  const float inv = 1.f / s;

  const float* offp = off + (size_t)bq*256 + (size_t)h*32;
  const float* rp   = ref + (size_t)bq*8;
  const float* vb   = v + (size_t)b*NV*256 + h*32 + lane;

  float acc = 0.f;
  #pragma unroll
  for (int l = 0; l < 4; ++l) {
    const int H = LH[l], W = LW[l];
    const float fW = (float)W, fH = (float)H;
    const float rx = rp[l*2+0], ry = rp[l*2+1];
    const float* vl = vb + (size_t)LS[l]*256;
    #pragma unroll
    for (int p = 0; p < 4; ++p) {
      const int ip = l*4 + p;
      const float ox = offp[ip*2+0], oy = offp[ip*2+1];
      const float x = (rx + ox / fW) * fW - 0.5f;
      const float y = (ry + oy / fH) * fH - 0.5f;
      const float x0f = floorf(x), y0f = floorf(y);
      const float lx = x - x0f, ly = y - y0f;
      const int x0 = (int)x0f, y0 = (int)y0f;
      const int x1 = x0 + 1,  y1 = y0 + 1;
      const int cx0 = min(max(x0, 0), W-1), cx1 = min(max(x1, 0), W-1);
      const int cy0 = min(max(y0, 0), H-1), cy1 = min(max(y1, 0), H-1);
      const float v00 = vl[(size_t)(cy0*W + cx0)*256];
      const float v10 = vl[(size_t)(cy0*W + cx1)*256];
      const float v01 = vl[(size_t)(cy1*W + cx0)*256];
      const float v11 = vl[(size_t)(cy1*W + cx1)*256];
      const float f00 = (x0 >= 0 && x0 < W && y0 >= 0 && y0 < H) ? 1.f : 0.f;
      const float f10 = (x1 >= 0 && x1 < W && y0 >= 0 && y0 < H) ? 1.f : 0.f;
      const float f01 = (x0 >= 0 && x0 < W && y1 >= 0 && y1 < H) ? 1.f : 0.f;
      const float f11 = (x1 >= 0 && x1 < W && y1 >= 0 && y1 < H) ? 1.f : 0.f;
      const float wt = w[ip] * inv;
      const float bil = (1.f-lx)*(1.f-ly)*f00*v00 + lx*(1.f-ly)*f10*v10
                      + (1.f-lx)*ly*f01*v01       + lx*ly*f11*v11;
      acc = fmaf(wt, bil, acc);
    }
  }
  attout[(size_t)bq*256 + (size_t)h*32 + lane] = acc;
}

extern "C" void kernel_launch(void* const* d_in, const int* in_sizes, int n_in,
                              void* d_out, int out_size, void* d_ws, size_t ws_size,
                              hipStream_t stream) {
  const float* query  = (const float*)d_in[0];
  // d_in[1] = key (unused by the reference forward)
  const float* value  = (const float*)d_in[2];
  const float* qpos   = (const float*)d_in[3];
  const float* refpts = (const float*)d_in[4];
  // d_in[5] spatial_shapes, d_in[6] level_start_index -> static constants
  // d_in[7] key_padding_mask -> all false in this problem
  const float* W_value = (const float*)d_in[8];
  const float* b_value = (const float*)d_in[9];
  const float* W_off   = (const float*)d_in[10];
  const float* b_off   = (const float*)d_in[11];
  const float* W_attn  = (const float*)d_in[12];
  const float* b_attn  = (const float*)d_in[13];
  const float* W_out   = (const float*)d_in[14];
  const float* b_out   = (const float*)d_in[15];
  const float* W_ffn   = (const float*)d_in[16];
  const float* b_ffn   = (const float*)d_in[17];
  float* out = (float*)d_out;

  const int M = M_ROWS;                       // 26588
  float* ws       = (float*)d_ws;
  const size_t sz256 = (size_t)M * 256;
  const size_t sz128 = (size_t)M * 128;
  float* off_buf  = ws;                       // (M,256)
  float* attn_buf = off_buf  + sz256;         // (M,128)
  float* v_buf    = attn_buf + sz128;         // (M,256)
  float* attout   = v_buf    + sz256;         // (M,256)
  float* tmp      = off_buf;                  // reuse after sampling

  const dim3 blk(256);
  const int gy = (M + 63) / 64;               // 416

  // v = value @ W_value + b_value
  gemm_f32<false,false><<<dim3(4, gy), blk, 0, stream>>>(
      value, nullptr, W_value, b_value, nullptr, v_buf, M, 256, 256);
  // off = (query+qpos) @ W_off + b_off
  gemm_f32<true,false><<<dim3(4, gy), blk, 0, stream>>>(
      query, qpos, W_off, b_off, nullptr, off_buf, M, 256, 256);
  // attn logits = (query+qpos) @ W_attn + b_attn
  gemm_f32<true,false><<<dim3(2, gy), blk, 0, stream>>>(
      query, qpos, W_attn, b_attn, nullptr, attn_buf, M, 128, 256);
  // deformable sampling -> attout
  msda_sample<<<dim3((2*NQ*8 + 7) / 8), blk, 0, stream>>>(
      v_buf, off_buf, attn_buf, refpts, attout);
  // tmp = attout @ W_out + b_out + query   (residual fused)
  gemm_f32<false,true><<<dim3(4, gy), blk, 0, stream>>>(
      attout, nullptr, W_out, b_out, query, tmp, M, 256, 256);
  // out = tmp @ W_ffn + b_ffn
  gemm_f32<false,false><<<dim3(4, gy), blk, 0, stream>>>(
      tmp, nullptr, W_ffn, b_ffn, nullptr, out, M, 256, 256);
}

// Round 3
// 365.446 us; speedup vs baseline: 1.9603x; 1.9603x over previous
//
#include <hip/hip_runtime.h>
#include <hip/hip_bf16.h>
#include <math.h>

#define NQ 13294
#define NV 13294
#define M_ROWS (2*NQ)

__device__ __forceinline__ float4 ld4(const float* p){ return *(const float4*)p; }
__device__ __forceinline__ float bfu(unsigned short u){ return __uint_as_float(((unsigned int)u) << 16); }
__device__ __forceinline__ unsigned short f2bf(float f){
  unsigned int u = __float_as_uint(f);
  u += 0x7fffu + ((u >> 16) & 1u);   // round-to-nearest-even
  return (unsigned short)(u >> 16);
}

// C = (A [+ A2]) @ B + bias [+ RES]; A: MxK row-major, B: KxN row-major, C: MxN
// OUT_BF16: store C as bf16 (packed ushort4 per 4 elems)
template<bool ADD_A2, bool ADD_RES, bool OUT_BF16>
__global__ __launch_bounds__(256) void gemm_f32(
    const float* __restrict__ A, const float* __restrict__ A2,
    const float* __restrict__ B, const float* __restrict__ bias,
    const float* __restrict__ RES, void* __restrict__ Cv,
    int M, int N, int K)
{
  __shared__ float As[16][64];   // [k][m]
  __shared__ float Bs[16][64];   // [k][n]
  const int tid  = threadIdx.x;
  const int trow = tid >> 4;     // 0..15
  const int tcol = tid & 15;     // 0..15
  const int brow = blockIdx.y * 64;
  const int bcol = blockIdx.x * 64;

  const int lar = tid >> 2;          // A tile row 0..63
  const int lak = (tid & 3) * 4;     // A tile k   0,4,8,12
  const int lbr = tid >> 4;          // B tile row 0..15
  const int lbc = (tid & 15) * 4;    // B tile col

  const int arow = brow + lar;
  const bool a_ok = arow < M;

  float acc[4][4] = {};

  for (int k0 = 0; k0 < K; k0 += 16) {
    float4 a4 = make_float4(0.f,0.f,0.f,0.f);
    if (a_ok) {
      a4 = ld4(A + (size_t)arow*K + k0 + lak);
      if (ADD_A2) {
        float4 p4 = ld4(A2 + (size_t)arow*K + k0 + lak);
        a4.x += p4.x; a4.y += p4.y; a4.z += p4.z; a4.w += p4.w;
      }
    }
    float4 b4 = ld4(B + (size_t)(k0 + lbr)*N + bcol + lbc);

    __syncthreads();
    As[lak+0][lar] = a4.x;
    As[lak+1][lar] = a4.y;
    As[lak+2][lar] = a4.z;
    As[lak+3][lar] = a4.w;
    *(float4*)&Bs[lbr][lbc] = b4;
    __syncthreads();

    #pragma unroll
    for (int kk = 0; kk < 16; ++kk) {
      float4 av = *(const float4*)&As[kk][trow*4];
      float4 bv = *(const float4*)&Bs[kk][tcol*4];
      float aa[4] = {av.x, av.y, av.z, av.w};
      float bb[4] = {bv.x, bv.y, bv.z, bv.w};
      #pragma unroll
      for (int i = 0; i < 4; ++i)
        #pragma unroll
        for (int j = 0; j < 4; ++j)
          acc[i][j] = fmaf(aa[i], bb[j], acc[i][j]);
    }
  }

  #pragma unroll
  for (int i = 0; i < 4; ++i) {
    int r = brow + trow*4 + i;
    if (r >= M) continue;
    if (OUT_BF16) {
      unsigned short* C = (unsigned short*)Cv;
      ushort4 pk;
      unsigned short* pp = (unsigned short*)&pk;
      #pragma unroll
      for (int j = 0; j < 4; ++j) {
        int c = bcol + tcol*4 + j;
        pp[j] = f2bf(acc[i][j] + bias[c]);
      }
      *(ushort4*)&C[(size_t)r*N + bcol + tcol*4] = pk;
    } else {
      float* C = (float*)Cv;
      #pragma unroll
      for (int j = 0; j < 4; ++j) {
        int c = bcol + tcol*4 + j;
        float vv = acc[i][j] + bias[c];
        if (ADD_RES) vv += RES[(size_t)r*N + c];
        C[(size_t)r*N + c] = vv;
      }
    }
  }
}

// Split-phase multi-scale deformable sampling.
// One block = one (b,q) = 8 groups (heads) x 32 lanes (channels).
// Phase 1: 16 lanes/group compute softmax + bilinear indices/weights -> LDS.
// Phase 2: 32 lanes/group gather bf16 v and accumulate.
__global__ __launch_bounds__(256) void msda_sample2(
    const unsigned short* __restrict__ v, const float* __restrict__ off,
    const float* __restrict__ lgt, const float* __restrict__ ref,
    float* __restrict__ attout)
{
  constexpr int LW[4] = {100, 50, 25, 13};
  constexpr int LH[4] = {100, 50, 25, 13};
  constexpr int LS[4] = {0, 10000, 12500, 13125};

  __shared__ int4   sidx[8][17];   // [head][point] corner element offsets (padded)
  __shared__ float4 swt [8][17];   // [head][point] premultiplied weights

  // bijective XCD-chunked swizzle over nwg = 2*NQ blocks
  const int nwg = 2 * NQ;
  const int qq = nwg >> 3, rr = nwg & 7;
  const int xcd = blockIdx.x & 7, sub = blockIdx.x >> 3;
  const int bq = (xcd < rr ? xcd * (qq + 1) : rr * (qq + 1) + (xcd - rr) * qq) + sub;

  const int gi   = threadIdx.x >> 5;   // head 0..7
  const int lane = threadIdx.x & 31;   // channel 0..31
  const int b    = (bq >= NQ) ? 1 : 0;

  if (lane < 16) {
    const int p = lane;          // point 0..15
    const int l = p >> 2;        // level
    const int W = LW[l], H = LH[l];
    const float fW = (float)W, fH = (float)H;

    float logit = lgt[(size_t)bq * 128 + gi * 16 + p];
    float mx = logit;
    #pragma unroll
    for (int m = 1; m < 16; m <<= 1) mx = fmaxf(mx, __shfl_xor(mx, m));
    float e = __expf(logit - mx);
    float sum = e;
    #pragma unroll
    for (int m = 1; m < 16; m <<= 1) sum += __shfl_xor(sum, m);
    const float wt = e / sum;

    const float* op = off + (size_t)bq * 256 + gi * 32 + p * 2;
    const float ox = op[0], oy = op[1];
    const float rx = ref[(size_t)bq * 8 + l * 2];
    const float ry = ref[(size_t)bq * 8 + l * 2 + 1];

    const float x = (rx + ox / fW) * fW - 0.5f;
    const float y = (ry + oy / fH) * fH - 0.5f;
    const float x0f = floorf(x), y0f = floorf(y);
    const float lx = x - x0f, ly = y - y0f;
    const int x0 = (int)x0f, y0 = (int)y0f;
    const int x1 = x0 + 1,  y1 = y0 + 1;
    const int cx0 = min(max(x0, 0), W - 1), cx1 = min(max(x1, 0), W - 1);
    const int cy0 = min(max(y0, 0), H - 1), cy1 = min(max(y1, 0), H - 1);
    const float f00 = (x0 >= 0 && x0 < W && y0 >= 0 && y0 < H) ? 1.f : 0.f;
    const float f10 = (x1 >= 0 && x1 < W && y0 >= 0 && y0 < H) ? 1.f : 0.f;
    const float f01 = (x0 >= 0 && x0 < W && y1 >= 0 && y1 < H) ? 1.f : 0.f;
    const float f11 = (x1 >= 0 && x1 < W && y1 >= 0 && y1 < H) ? 1.f : 0.f;

    const int base = LS[l] * 256 + gi * 32;
    sidx[gi][p] = make_int4(base + (cy0 * W + cx0) * 256,
                            base + (cy0 * W + cx1) * 256,
                            base + (cy1 * W + cx0) * 256,
                            base + (cy1 * W + cx1) * 256);
    swt[gi][p] = make_float4(wt * (1.f - lx) * (1.f - ly) * f00,
                             wt * lx * (1.f - ly) * f10,
                             wt * (1.f - lx) * ly * f01,
                             wt * lx * ly * f11);
  }
  __syncthreads();

  const unsigned short* vb = v + (size_t)b * NV * 256;
  float acc = 0.f;
  #pragma unroll
  for (int p = 0; p < 16; ++p) {
    const int4   ix = sidx[gi][p];
    const float4 w4 = swt[gi][p];
    const float s0 = bfu(vb[ix.x + lane]);
    const float s1 = bfu(vb[ix.y + lane]);
    const float s2 = bfu(vb[ix.z + lane]);
    const float s3 = bfu(vb[ix.w + lane]);
    acc = fmaf(w4.x, s0, acc);
    acc = fmaf(w4.y, s1, acc);
    acc = fmaf(w4.z, s2, acc);
    acc = fmaf(w4.w, s3, acc);
  }
  attout[(size_t)bq * 256 + gi * 32 + lane] = acc;
}

extern "C" void kernel_launch(void* const* d_in, const int* in_sizes, int n_in,
                              void* d_out, int out_size, void* d_ws, size_t ws_size,
                              hipStream_t stream) {
  const float* query  = (const float*)d_in[0];
  const float* value  = (const float*)d_in[2];
  const float* qpos   = (const float*)d_in[3];
  const float* refpts = (const float*)d_in[4];
  const float* W_value = (const float*)d_in[8];
  const float* b_value = (const float*)d_in[9];
  const float* W_off   = (const float*)d_in[10];
  const float* b_off   = (const float*)d_in[11];
  const float* W_attn  = (const float*)d_in[12];
  const float* b_attn  = (const float*)d_in[13];
  const float* W_out   = (const float*)d_in[14];
  const float* b_out   = (const float*)d_in[15];
  const float* W_ffn   = (const float*)d_in[16];
  const float* b_ffn   = (const float*)d_in[17];
  float* out = (float*)d_out;

  const int M = M_ROWS;                       // 26588
  float* ws       = (float*)d_ws;
  const size_t sz256 = (size_t)M * 256;
  const size_t sz128 = (size_t)M * 128;
  float* off_buf  = ws;                            // (M,256) f32
  float* attn_buf = off_buf  + sz256;              // (M,128) f32
  unsigned short* v_buf = (unsigned short*)(attn_buf + sz128);   // (M,256) bf16
  float* attout   = (float*)((char*)v_buf + sz256 * sizeof(unsigned short)); // (M,256) f32
  float* tmp      = off_buf;                       // reuse after sampling

  const dim3 blk(256);
  const int gy = (M + 63) / 64;               // 416

  // v = value @ W_value + b_value   (bf16 output for the sampler)
  gemm_f32<false,false,true><<<dim3(4, gy), blk, 0, stream>>>(
      value, nullptr, W_value, b_value, nullptr, v_buf, M, 256, 256);
  // off = (query+qpos) @ W_off + b_off
  gemm_f32<true,false,false><<<dim3(4, gy), blk, 0, stream>>>(
      query, qpos, W_off, b_off, nullptr, off_buf, M, 256, 256);
  // attn logits = (query+qpos) @ W_attn + b_attn
  gemm_f32<true,false,false><<<dim3(2, gy), blk, 0, stream>>>(
      query, qpos, W_attn, b_attn, nullptr, attn_buf, M, 128, 256);
  // deformable sampling -> attout
  msda_sample2<<<dim3(2*NQ), blk, 0, stream>>>(
      v_buf, off_buf, attn_buf, refpts, attout);
  // tmp = attout @ W_out + b_out + query   (residual fused)
  gemm_f32<false,true,false><<<dim3(4, gy), blk, 0, stream>>>(
      attout, nullptr, W_out, b_out, query, tmp, M, 256, 256);
  // out = tmp @ W_ffn + b_ffn
  gemm_f32<false,false,false><<<dim3(4, gy), blk, 0, stream>>>(
      tmp, nullptr, W_ffn, b_ffn, nullptr, out, M, 256, 256);
}

// Round 4
// 204.342 us; speedup vs baseline: 3.5058x; 1.7884x over previous
//
#include <hip/hip_runtime.h>
#include <hip/hip_bf16.h>
#include <math.h>

#define NQ 13294
#define NV 13294
#define M_ROWS (2*NQ)     // 26588
#define MP 26624          // padded to 128*208

typedef __attribute__((ext_vector_type(8))) short bf16x8;
typedef __attribute__((ext_vector_type(4))) float f32x4;

__device__ __forceinline__ float4 ld4(const float* p){ return *(const float4*)p; }
__device__ __forceinline__ float bfu_lo(unsigned int u){ return __uint_as_float(u << 16); }
__device__ __forceinline__ float bfu_hi(unsigned int u){ return __uint_as_float(u & 0xffff0000u); }
__device__ __forceinline__ unsigned short f2bf(float f){
  unsigned int u = __float_as_uint(f);
  u += 0x7fffu + ((u >> 16) & 1u);   // RNE
  return (unsigned short)(u >> 16);
}

// ---- prep: value -> bf16, (query+qpos) -> bf16, zero-pad rows M..MP ----
__global__ __launch_bounds__(256) void prep_a(
    const float* __restrict__ value, const float* __restrict__ query,
    const float* __restrict__ qpos,
    unsigned short* __restrict__ val_bf, unsigned short* __restrict__ q_bf)
{
  const int total = MP * 64;   // float4 groups
  for (int i = blockIdx.x * 256 + threadIdx.x; i < total; i += gridDim.x * 256) {
    const int e = i * 4;
    ushort4 a = make_ushort4(0,0,0,0), b = make_ushort4(0,0,0,0);
    if (e < M_ROWS * 256) {
      float4 v4 = ld4(value + e);
      a = make_ushort4(f2bf(v4.x), f2bf(v4.y), f2bf(v4.z), f2bf(v4.w));
      float4 q4 = ld4(query + e);
      float4 p4 = ld4(qpos + e);
      b = make_ushort4(f2bf(q4.x+p4.x), f2bf(q4.y+p4.y), f2bf(q4.z+p4.z), f2bf(q4.w+p4.w));
    }
    *(ushort4*)(val_bf + e) = a;
    *(ushort4*)(q_bf   + e) = b;
  }
}

// ---- prep: transpose 5 weights f32 [K][N] -> bf16 [N][K] (K=256) ----
__global__ __launch_bounds__(256) void prep_w(
    const float* __restrict__ wv, const float* __restrict__ wo,
    const float* __restrict__ wa, const float* __restrict__ wu,
    const float* __restrict__ wf, unsigned short* __restrict__ wt)
{
  int t = blockIdx.x * 256 + threadIdx.x;
  if (t >= 294912) return;
  const float* src; int Nn; int base;
  if      (t < 65536)  { src = wv; Nn = 256; base = 0; }
  else if (t < 131072) { src = wo; Nn = 256; base = 65536; }
  else if (t < 163840) { src = wa; Nn = 128; base = 131072; }
  else if (t < 229376) { src = wu; Nn = 256; base = 163840; }
  else                 { src = wf; Nn = 256; base = 229376; }
  const int local = t - base;
  const int n = local >> 8, k = local & 255;
  wt[t] = f2bf(src[k * Nn + n]);
}

// ---- bf16 MFMA GEMM: C = A @ Bt^T + bias [+ RES]; A:[MP][256] bf16,
// Bt:[N][256] bf16 (pre-transposed weights), C:[M][N] ----
template<bool OUT_BF16, bool ADD_RES>
__global__ __launch_bounds__(256) void gemm_mfma(
    const unsigned short* __restrict__ A, const unsigned short* __restrict__ Bt,
    const float* __restrict__ bias, const float* __restrict__ RES,
    void* __restrict__ Cv, int M_, int N)
{
  __shared__ unsigned short As[128 * 64];  // [row][k] bf16, XOR-swizzled
  __shared__ unsigned short Bs[128 * 64];  // [col][k] bf16, XOR-swizzled

  const int tid  = threadIdx.x;
  const int brow = blockIdx.x * 128;
  const int bcol = blockIdx.y * 128;
  const int wid  = tid >> 6, lane = tid & 63;
  const int wr   = wid >> 1, wc = wid & 1;
  const int fr   = lane & 15, fg = lane >> 4;

  const int srow = tid >> 3;          // 0..31 (within chunk)
  const int scb  = (tid & 7) << 4;    // byte col 0..112

  f32x4 acc[4][4];
  #pragma unroll
  for (int m = 0; m < 4; ++m)
    #pragma unroll
    for (int n = 0; n < 4; ++n)
      acc[m][n] = (f32x4){0.f, 0.f, 0.f, 0.f};

  for (int k0 = 0; k0 < 256; k0 += 64) {
    uint4 ar[4], br[4];
    #pragma unroll
    for (int c = 0; c < 4; ++c) {
      const int row = c * 32 + srow;
      ar[c] = *(const uint4*)(A  + (size_t)(brow + row) * 256 + k0 + (scb >> 1));
      br[c] = *(const uint4*)(Bt + (size_t)(bcol + row) * 256 + k0 + (scb >> 1));
    }
    __syncthreads();
    #pragma unroll
    for (int c = 0; c < 4; ++c) {
      const int row = c * 32 + srow;
      const int sc  = (scb ^ ((row & 7) << 4)) >> 1;
      *(uint4*)&As[row * 64 + sc] = ar[c];
      *(uint4*)&Bs[row * 64 + sc] = br[c];
    }
    __syncthreads();
    #pragma unroll
    for (int kk = 0; kk < 2; ++kk) {
      const int kb = kk * 64 + fg * 16;  // byte col of this lane's k-chunk
      bf16x8 af[4], bfr[4];
      #pragma unroll
      for (int m = 0; m < 4; ++m) {
        const int r = wr * 64 + m * 16 + fr;
        af[m] = *(const bf16x8*)&As[r * 64 + ((kb ^ ((r & 7) << 4)) >> 1)];
      }
      #pragma unroll
      for (int n = 0; n < 4; ++n) {
        const int r = wc * 64 + n * 16 + fr;
        bfr[n] = *(const bf16x8*)&Bs[r * 64 + ((kb ^ ((r & 7) << 4)) >> 1)];
      }
      #pragma unroll
      for (int m = 0; m < 4; ++m)
        #pragma unroll
        for (int n = 0; n < 4; ++n)
          acc[m][n] = __builtin_amdgcn_mfma_f32_16x16x32_bf16(af[m], bfr[n], acc[m][n], 0, 0, 0);
    }
  }

  // epilogue
  int cn[4]; float bn[4];
  #pragma unroll
  for (int n = 0; n < 4; ++n) {
    cn[n] = bcol + wc * 64 + n * 16 + fr;
    bn[n] = bias[cn[n]];
  }
  #pragma unroll
  for (int m = 0; m < 4; ++m) {
    #pragma unroll
    for (int j = 0; j < 4; ++j) {
      const int r = brow + wr * 64 + m * 16 + fg * 4 + j;
      if (r >= M_) continue;
      #pragma unroll
      for (int n = 0; n < 4; ++n) {
        float vv = acc[m][n][j] + bn[n];
        if (ADD_RES) vv += RES[(size_t)r * 256 + cn[n]];
        if (OUT_BF16) ((unsigned short*)Cv)[(size_t)r * N + cn[n]] = f2bf(vv);
        else          ((float*)Cv)[(size_t)r * N + cn[n]] = vv;
      }
    }
  }
}

// ---- deformable sampling: 8 queries/block, 4 lanes per (q,h), 8 ch/lane ----
__global__ __launch_bounds__(256) void msda3(
    const unsigned short* __restrict__ v, const float* __restrict__ off,
    const float* __restrict__ lgt, const float* __restrict__ ref,
    unsigned short* __restrict__ attout)
{
  constexpr int LW[4] = {100, 50, 25, 13};
  constexpr int LH[4] = {100, 50, 25, 13};
  constexpr int LS[4] = {0, 10000, 12500, 13125};

  __shared__ int4   sidx[8][8][16];
  __shared__ float4 swt [8][8][16];

  // bijective XCD-chunked swizzle over nwg = 3324 blocks
  const int nwg = (M_ROWS + 7) / 8;            // 3324
  const int qq = nwg >> 3, rr = nwg & 7;
  const int xcd = blockIdx.x & 7, sub = blockIdx.x >> 3;
  const int wg = (xcd < rr ? xcd * (qq + 1) : rr * (qq + 1) + (xcd - rr) * qq) + sub;

  const int tid = threadIdx.x;
  const int qi  = tid >> 5;          // query within block 0..7
  const int h   = (tid >> 2) & 7;    // head
  const int lq  = tid & 3;           // lane quad: level in phase1, chan-octet in phase2
  const int bq  = wg * 8 + qi;
  const bool active = bq < M_ROWS;
  const int b = (bq >= NQ) ? 1 : 0;

  if (active) {
    const int l = lq;
    const int W = LW[l], H = LH[l];
    const float fW = (float)W, fH = (float)H;

    float4 lg4 = ld4(lgt + (size_t)bq * 128 + h * 16 + l * 4);
    float mx = fmaxf(fmaxf(lg4.x, lg4.y), fmaxf(lg4.z, lg4.w));
    mx = fmaxf(mx, __shfl_xor(mx, 1));
    mx = fmaxf(mx, __shfl_xor(mx, 2));
    float e[4] = {__expf(lg4.x - mx), __expf(lg4.y - mx), __expf(lg4.z - mx), __expf(lg4.w - mx)};
    float s = e[0] + e[1] + e[2] + e[3];
    s += __shfl_xor(s, 1);
    s += __shfl_xor(s, 2);
    const float inv = 1.f / s;

    const float rx = ref[(size_t)bq * 8 + l * 2];
    const float ry = ref[(size_t)bq * 8 + l * 2 + 1];
    float4 o1 = ld4(off + (size_t)bq * 256 + h * 32 + l * 8);
    float4 o2 = ld4(off + (size_t)bq * 256 + h * 32 + l * 8 + 4);
    const float oxy[8] = {o1.x, o1.y, o1.z, o1.w, o2.x, o2.y, o2.z, o2.w};

    #pragma unroll
    for (int j = 0; j < 4; ++j) {
      const float ox = oxy[2*j], oy = oxy[2*j+1];
      const float x = (rx + ox / fW) * fW - 0.5f;
      const float y = (ry + oy / fH) * fH - 0.5f;
      const float x0f = floorf(x), y0f = floorf(y);
      const float lx = x - x0f, ly = y - y0f;
      const int x0 = (int)x0f, y0 = (int)y0f;
      const int x1 = x0 + 1,  y1 = y0 + 1;
      const int cx0 = min(max(x0, 0), W - 1), cx1 = min(max(x1, 0), W - 1);
      const int cy0 = min(max(y0, 0), H - 1), cy1 = min(max(y1, 0), H - 1);
      const float f00 = (x0 >= 0 && x0 < W && y0 >= 0 && y0 < H) ? 1.f : 0.f;
      const float f10 = (x1 >= 0 && x1 < W && y0 >= 0 && y0 < H) ? 1.f : 0.f;
      const float f01 = (x0 >= 0 && x0 < W && y1 >= 0 && y1 < H) ? 1.f : 0.f;
      const float f11 = (x1 >= 0 && x1 < W && y1 >= 0 && y1 < H) ? 1.f : 0.f;
      const int base = LS[l] * 256 + h * 32;
      const float wt = e[j] * inv;
      sidx[qi][h][l*4+j] = make_int4(base + (cy0 * W + cx0) * 256,
                                     base + (cy0 * W + cx1) * 256,
                                     base + (cy1 * W + cx0) * 256,
                                     base + (cy1 * W + cx1) * 256);
      swt[qi][h][l*4+j] = make_float4(wt * (1.f - lx) * (1.f - ly) * f00,
                                      wt * lx * (1.f - ly) * f10,
                                      wt * (1.f - lx) * ly * f01,
                                      wt * lx * ly * f11);
    }
  }
  __syncthreads();

  if (active) {
    const unsigned short* vb = v + (size_t)b * NV * 256 + lq * 8;
    float acc[8] = {0.f, 0.f, 0.f, 0.f, 0.f, 0.f, 0.f, 0.f};
    #pragma unroll
    for (int p = 0; p < 16; ++p) {
      const int4   ix = sidx[qi][h][p];
      const float4 w4 = swt[qi][h][p];
      uint4 c0 = *(const uint4*)(vb + ix.x);
      uint4 c1 = *(const uint4*)(vb + ix.y);
      uint4 c2 = *(const uint4*)(vb + ix.z);
      uint4 c3 = *(const uint4*)(vb + ix.w);
      acc[0] = fmaf(w4.x, bfu_lo(c0.x), acc[0]); acc[1] = fmaf(w4.x, bfu_hi(c0.x), acc[1]);
      acc[2] = fmaf(w4.x, bfu_lo(c0.y), acc[2]); acc[3] = fmaf(w4.x, bfu_hi(c0.y), acc[3]);
      acc[4] = fmaf(w4.x, bfu_lo(c0.z), acc[4]); acc[5] = fmaf(w4.x, bfu_hi(c0.z), acc[5]);
      acc[6] = fmaf(w4.x, bfu_lo(c0.w), acc[6]); acc[7] = fmaf(w4.x, bfu_hi(c0.w), acc[7]);
      acc[0] = fmaf(w4.y, bfu_lo(c1.x), acc[0]); acc[1] = fmaf(w4.y, bfu_hi(c1.x), acc[1]);
      acc[2] = fmaf(w4.y, bfu_lo(c1.y), acc[2]); acc[3] = fmaf(w4.y, bfu_hi(c1.y), acc[3]);
      acc[4] = fmaf(w4.y, bfu_lo(c1.z), acc[4]); acc[5] = fmaf(w4.y, bfu_hi(c1.z), acc[5]);
      acc[6] = fmaf(w4.y, bfu_lo(c1.w), acc[6]); acc[7] = fmaf(w4.y, bfu_hi(c1.w), acc[7]);
      acc[0] = fmaf(w4.z, bfu_lo(c2.x), acc[0]); acc[1] = fmaf(w4.z, bfu_hi(c2.x), acc[1]);
      acc[2] = fmaf(w4.z, bfu_lo(c2.y), acc[2]); acc[3] = fmaf(w4.z, bfu_hi(c2.y), acc[3]);
      acc[4] = fmaf(w4.z, bfu_lo(c2.z), acc[4]); acc[5] = fmaf(w4.z, bfu_hi(c2.z), acc[5]);
      acc[6] = fmaf(w4.z, bfu_lo(c2.w), acc[6]); acc[7] = fmaf(w4.z, bfu_hi(c2.w), acc[7]);
      acc[0] = fmaf(w4.w, bfu_lo(c3.x), acc[0]); acc[1] = fmaf(w4.w, bfu_hi(c3.x), acc[1]);
      acc[2] = fmaf(w4.w, bfu_lo(c3.y), acc[2]); acc[3] = fmaf(w4.w, bfu_hi(c3.y), acc[3]);
      acc[4] = fmaf(w4.w, bfu_lo(c3.z), acc[4]); acc[5] = fmaf(w4.w, bfu_hi(c3.z), acc[5]);
      acc[6] = fmaf(w4.w, bfu_lo(c3.w), acc[6]); acc[7] = fmaf(w4.w, bfu_hi(c3.w), acc[7]);
    }
    uint4 pk;
    pk.x = (unsigned int)f2bf(acc[0]) | ((unsigned int)f2bf(acc[1]) << 16);
    pk.y = (unsigned int)f2bf(acc[2]) | ((unsigned int)f2bf(acc[3]) << 16);
    pk.z = (unsigned int)f2bf(acc[4]) | ((unsigned int)f2bf(acc[5]) << 16);
    pk.w = (unsigned int)f2bf(acc[6]) | ((unsigned int)f2bf(acc[7]) << 16);
    *(uint4*)(attout + (size_t)bq * 256 + h * 32 + lq * 8) = pk;
  }
}

extern "C" void kernel_launch(void* const* d_in, const int* in_sizes, int n_in,
                              void* d_out, int out_size, void* d_ws, size_t ws_size,
                              hipStream_t stream) {
  const float* query  = (const float*)d_in[0];
  const float* value  = (const float*)d_in[2];
  const float* qpos   = (const float*)d_in[3];
  const float* refpts = (const float*)d_in[4];
  const float* W_value = (const float*)d_in[8];
  const float* b_value = (const float*)d_in[9];
  const float* W_off   = (const float*)d_in[10];
  const float* b_off   = (const float*)d_in[11];
  const float* W_attn  = (const float*)d_in[12];
  const float* b_attn  = (const float*)d_in[13];
  const float* W_out   = (const float*)d_in[14];
  const float* b_out   = (const float*)d_in[15];
  const float* W_ffn   = (const float*)d_in[16];
  const float* b_ffn   = (const float*)d_in[17];
  float* out = (float*)d_out;

  const int M = M_ROWS;
  // workspace layout (82.4 MB)
  float* off_buf  = (float*)d_ws;                          // MP*256 f32
  float* attn_buf = off_buf + (size_t)MP * 256;            // MP*128 f32
  unsigned short* R1   = (unsigned short*)(attn_buf + (size_t)MP * 128); // val_bf / attout_bf
  unsigned short* R2   = R1 + (size_t)MP * 256;            // q_bf / tmp_bf
  unsigned short* vbuf = R2 + (size_t)MP * 256;            // v projection bf16
  unsigned short* wts  = vbuf + (size_t)MP * 256;          // 5 transposed weights
  unsigned short* wv_t = wts;
  unsigned short* wo_t = wts + 65536;
  unsigned short* wa_t = wts + 131072;
  unsigned short* wu_t = wts + 163840;
  unsigned short* wf_t = wts + 229376;

  const dim3 blk(256);

  prep_a<<<dim3(2048), blk, 0, stream>>>(value, query, qpos, R1, R2);
  prep_w<<<dim3(1152), blk, 0, stream>>>(W_value, W_off, W_attn, W_out, W_ffn, wts);

  // v = value @ W_value + b  -> bf16
  gemm_mfma<true,false><<<dim3(208, 2), blk, 0, stream>>>(R1, wv_t, b_value, nullptr, vbuf, M, 256);
  // off = (q+pos) @ W_off + b -> f32
  gemm_mfma<false,false><<<dim3(208, 2), blk, 0, stream>>>(R2, wo_t, b_off, nullptr, off_buf, M, 256);
  // attn logits = (q+pos) @ W_attn + b -> f32
  gemm_mfma<false,false><<<dim3(208, 1), blk, 0, stream>>>(R2, wa_t, b_attn, nullptr, attn_buf, M, 128);
  // sampling -> attout bf16 (reuses R1)
  msda3<<<dim3((M_ROWS + 7) / 8), blk, 0, stream>>>(vbuf, off_buf, attn_buf, refpts, R1);
  // tmp = attout @ W_out + b + query -> bf16 (reuses R2)
  gemm_mfma<true,true><<<dim3(208, 2), blk, 0, stream>>>(R1, wu_t, b_out, query, R2, M, 256);
  // out = tmp @ W_ffn + b -> f32
  gemm_mfma<false,false><<<dim3(208, 2), blk, 0, stream>>>(R2, wf_t, b_ffn, nullptr, (void*)out, M, 256);
}